// Round 4
// baseline (73.430 us; speedup 1.0000x reference)
//
#include <hip/hip_runtime.h>
#include <stdint.h>

#define MROWS 131072
#define NSPEC 8
#define DIN   128
#define NOUT  256
#define BM    64

typedef __attribute__((ext_vector_type(8))) short s16x8;
typedef __attribute__((ext_vector_type(4))) float f32x4;
typedef __attribute__((ext_vector_type(4))) unsigned int u32x4;

// workspace layout
#define OFF_BF    ((size_t)0)        // 8*16*4*1024 = 524288 B : W in bf16, fragment order
#define OFF_PERM  ((size_t)524288)   // M*4 = 524288 B : row permutation (sorted by species)
#define OFF_META  ((size_t)1048576)  // ints: counts[8], cursors[8]  (zeroed by memsetAsync)
#define WS_NEEDED ((size_t)(1048576 + 256))

__device__ __forceinline__ uint32_t bf16_bits(uint32_t u) {
  return (u + 0x7FFFu + ((u >> 16) & 1u)) >> 16;   // RNE, inputs finite
}
__device__ __forceinline__ uint32_t bf16_1(float f) {
  union { float f; uint32_t u; } v; v.f = f;
  return bf16_bits(v.u);
}

// blocks 0..127: convert W [8][128][256] fp32 -> bf16 fragment order.
//   chunk c = ((s*16 + nfrag)*4 + kt); lane l holds
//   B[k = kt*32 + (l>>4)*8 + j][n = nfrag*16 + (l&15)], j=0..7 (16B contiguous).
// blocks 128..639: histogram species -> counts[8] (curs zeroed by memset).
__global__ void k_convert_hist(const float* __restrict__ B, const int* __restrict__ sp,
                               char* __restrict__ ws) {
  int blk = blockIdx.x;
  int t = threadIdx.x;
  if (blk < 128) {
    int gid = blk * 256 + t;                  // 32768 threads
    int l  = gid & 63;
    int c  = gid >> 6;                        // 0..511
    int kt = c & 3;
    int f  = (c >> 2) & 15;
    int s  = c >> 6;
    int n  = f * 16 + (l & 15);
    int k0 = kt * 32 + (l >> 4) * 8;
    const float* src = B + (size_t)s * DIN * NOUT + n;
    uint32_t w0 = bf16_1(src[(size_t)(k0 + 0) * NOUT]) | (bf16_1(src[(size_t)(k0 + 1) * NOUT]) << 16);
    uint32_t w1 = bf16_1(src[(size_t)(k0 + 2) * NOUT]) | (bf16_1(src[(size_t)(k0 + 3) * NOUT]) << 16);
    uint32_t w2 = bf16_1(src[(size_t)(k0 + 4) * NOUT]) | (bf16_1(src[(size_t)(k0 + 5) * NOUT]) << 16);
    uint32_t w3 = bf16_1(src[(size_t)(k0 + 6) * NOUT]) | (bf16_1(src[(size_t)(k0 + 7) * NOUT]) << 16);
    u32x4 v = (u32x4){w0, w1, w2, w3};
    *(u32x4*)(ws + OFF_BF + (size_t)c * 1024 + (size_t)l * 16) = v;
  } else {
    __shared__ int bins[8];
    int* counts = (int*)(ws + OFF_META);
    if (t < 8) bins[t] = 0;
    __syncthreads();
    atomicAdd(&bins[sp[(blk - 128) * 256 + t] & 7], 1);
    __syncthreads();
    if (t < 8) atomicAdd(&counts[t], bins[t]);
  }
}

// Scatter: each block recomputes the 8-wide exclusive prefix of counts itself;
// block-local rank + one global cursor bump per species.
__global__ void k_scatter(const int* __restrict__ sp, char* __restrict__ ws) {
  __shared__ int lbin[8], gbase[8];
  int* counts = (int*)(ws + OFF_META);
  int* curs   = counts + 8;                   // zeroed by memsetAsync each call
  int* perm   = (int*)(ws + OFF_PERM);
  int t = threadIdx.x;
  if (t < 8) lbin[t] = 0;
  __syncthreads();
  int i = blockIdx.x * 256 + t;
  int s = sp[i] & 7;
  int rank = atomicAdd(&lbin[s], 1);          // within-block rank
  __syncthreads();
  if (t < 8) {
    int base = 0;
    #pragma unroll
    for (int j = 0; j < 8; ++j) base += (j < t) ? counts[j] : 0;
    gbase[t] = base + atomicAdd(&curs[t], lbin[t]);
  }
  __syncthreads();
  perm[gbase[s] + rank] = i;                  // order within species irrelevant
}

// One block = 64 rows (uniform species, via perm) x 256 cols. 4 waves, each 64x64.
__global__ __launch_bounds__(256) void k_gemm(const float* __restrict__ A,
                                              const char* __restrict__ ws,
                                              float* __restrict__ out) {
  const int* counts = (const int*)(ws + OFF_META);
  const int* perm   = (const int*)(ws + OFF_PERM);
  const char* Bf    = ws + OFF_BF;

  __shared__ char As[BM * 256];   // [64 rows][128 k] bf16 swizzled; reused as fp32 transpose buf
  __shared__ int prow[BM];

  // recompute bases/tile offsets from counts (8 uniform loads, register scan)
  int b = blockIdx.x;
  int s = -1, i = 0, rowStart = 0, nrows = 0;
  {
    int base = 0, toff = 0;
    #pragma unroll
    for (int j = 0; j < 8; ++j) {
      int c = counts[j];
      int nt = (c + BM - 1) >> 6;
      if (s < 0 && b < toff + nt) {
        s = j; i = b - toff;
        rowStart = base + i * BM;
        nrows = c - i * BM; if (nrows > BM) nrows = BM;
      }
      base += c; toff += nt;
    }
    if (s < 0) return;                        // past last tile
  }

  int t = threadIdx.x;
  if (t < BM) prow[t] = (t < nrows) ? perm[rowStart + t] : -1;
  __syncthreads();

  // stage A: 8 rows per iteration, 32 threads per row (float4 each), fp32->bf16
  // nontemporal: A is read-once streaming; keep L2 for B-fragments.
  int f4 = t & 31, r0 = t >> 5;
  #pragma unroll
  for (int it = 0; it < 8; ++it) {
    int r = r0 + it * 8;
    int rid = prow[r];
    u32x4 u = (u32x4){0u, 0u, 0u, 0u};
    if (rid >= 0) u = __builtin_nontemporal_load((const u32x4*)(A + (size_t)rid * DIN + f4 * 4));
    uint32_t lo = bf16_bits(u.x) | (bf16_bits(u.y) << 16);
    uint32_t hi = bf16_bits(u.z) | (bf16_bits(u.w) << 16);
    int off = (r * 256 + f4 * 8) ^ ((r & 7) << 4);   // G4 swizzle
    *(uint2*)(As + off) = make_uint2(lo, hi);
  }
  __syncthreads();

  int w = t >> 6, l = t & 63;
  f32x4 acc[4][4];
  #pragma unroll
  for (int mi = 0; mi < 4; ++mi)
    #pragma unroll
    for (int ni = 0; ni < 4; ++ni)
      acc[mi][ni] = (f32x4){0.f, 0.f, 0.f, 0.f};

  #pragma unroll
  for (int kt = 0; kt < 4; ++kt) {
    s16x8 afr[4];
    #pragma unroll
    for (int mi = 0; mi < 4; ++mi) {
      int r = mi * 16 + (l & 15);
      int off = (r * 256 + kt * 64 + (l >> 4) * 16) ^ ((r & 7) << 4);
      afr[mi] = *(const s16x8*)(As + off);
    }
    #pragma unroll
    for (int ni = 0; ni < 4; ++ni) {
      int c = (s * 16 + (w * 4 + ni)) * 4 + kt;
      s16x8 bfr = *(const s16x8*)(Bf + (size_t)c * 1024 + (size_t)l * 16);
      #pragma unroll
      for (int mi = 0; mi < 4; ++mi)
        acc[mi][ni] = __builtin_amdgcn_mfma_f32_16x16x32_bf16(afr[mi], bfr, acc[mi][ni], 0, 0, 0);
    }
  }

  // ---- epilogue: transpose 16-row chunks through LDS (reuse As, 16KB) so each
  // store instruction is one FULL 1KB contiguous row (64 lanes x dwordx4).
  // LDS swizzle: off ^= ((off>>12)&1)<<6  -> transpose writes 2-way (free, m136).
  #pragma unroll
  for (int mi = 0; mi < 4; ++mi) {
    __syncthreads();                          // As free (compute done / prev chunk read)
    #pragma unroll
    for (int ni = 0; ni < 4; ++ni) {
      int col4 = (w * 64 + ni * 16 + (l & 15)) * 4;
      #pragma unroll
      for (int q = 0; q < 4; ++q) {
        int r16 = ((l >> 4) << 2) + q;        // row within chunk
        int off = r16 * 1024 + col4;
        off ^= ((off >> 12) & 1) << 6;
        *(float*)(As + off) = acc[mi][ni][q];
      }
    }
    __syncthreads();
    #pragma unroll
    for (int q = 0; q < 4; ++q) {
      int r16 = w * 4 + q;                    // each wave stores 4 full rows
      int rid = prow[mi * 16 + r16];
      int off = r16 * 1024 + l * 16;
      off ^= ((off >> 12) & 1) << 6;
      u32x4 v = *(const u32x4*)(As + off);
      if (rid >= 0)
        __builtin_nontemporal_store(v, (u32x4*)(out + (size_t)rid * NOUT) + l);
    }
  }
}

// ws-free correctness fallback (only if ws_size is unexpectedly small)
__global__ void k_naive(const float* __restrict__ A, const int* __restrict__ sp,
                        const float* __restrict__ B, float* __restrict__ out) {
  __shared__ float av[DIN];
  int m = blockIdx.x;
  int n = threadIdx.x;
  if (n < DIN) av[n] = A[(size_t)m * DIN + n];
  __syncthreads();
  int s = sp[m] & 7;
  const float* b = B + (size_t)s * DIN * NOUT + n;
  float acc = 0.f;
  #pragma unroll 8
  for (int k = 0; k < DIN; ++k) acc = fmaf(av[k], b[(size_t)k * NOUT], acc);
  out[(size_t)m * NOUT + n] = acc;
}

extern "C" void kernel_launch(void* const* d_in, const int* in_sizes, int n_in,
                              void* d_out, int out_size, void* d_ws, size_t ws_size,
                              hipStream_t stream) {
  const float* values = (const float*)d_in[0];
  const int*   sp     = (const int*)d_in[1];
  const float* B      = (const float*)d_in[2];
  float*       out    = (float*)d_out;

  if (d_ws == nullptr || ws_size < WS_NEEDED) {
    k_naive<<<MROWS, NOUT, 0, stream>>>(values, sp, B, out);
    return;
  }
  char* ws = (char*)d_ws;
  (void)hipMemsetAsync(ws + OFF_META, 0, 64, stream);           // counts+curs = 0
  k_convert_hist<<<128 + MROWS / 256, 256, 0, stream>>>(B, sp, ws);
  k_scatter<<<MROWS / 256, 256, 0, stream>>>(sp, ws);
  k_gemm<<<MROWS / BM + NSPEC, 256, 0, stream>>>(values, ws, out);
}

// Round 5
// 72.679 us; speedup vs baseline: 1.0103x; 1.0103x over previous
//
#include <hip/hip_runtime.h>
#include <stdint.h>

#define MROWS 131072
#define NSPEC 8
#define DIN   128
#define NOUT  256
#define BM    64

typedef __attribute__((ext_vector_type(8))) short s16x8;
typedef __attribute__((ext_vector_type(4))) float f32x4;
typedef __attribute__((ext_vector_type(4))) unsigned int u32x4;

// workspace layout
#define OFF_BF    ((size_t)0)        // 8*16*4*1024 = 524288 B : W in bf16, fragment order
#define OFF_PERM  ((size_t)524288)   // M*4 = 524288 B : row permutation (sorted by species)
#define OFF_META  ((size_t)1048576)  // ints: counts[8], cursors[8]  (zeroed by memsetAsync)
#define WS_NEEDED ((size_t)(1048576 + 256))

__device__ __forceinline__ uint32_t bf16_bits(uint32_t u) {
  return (u + 0x7FFFu + ((u >> 16) & 1u)) >> 16;   // RNE, inputs finite
}
__device__ __forceinline__ uint32_t bf16_1(float f) {
  union { float f; uint32_t u; } v; v.f = f;
  return bf16_bits(v.u);
}

// blocks 0..127: convert W [8][128][256] fp32 -> bf16 fragment order.
//   chunk c = ((s*16 + nfrag)*4 + kt); lane l holds
//   B[k = kt*32 + (l>>4)*8 + j][n = nfrag*16 + (l&15)], j=0..7 (16B contiguous).
// blocks 128..639: histogram species -> counts[8] (curs zeroed by memset).
__global__ void k_convert_hist(const float* __restrict__ B, const int* __restrict__ sp,
                               char* __restrict__ ws) {
  int blk = blockIdx.x;
  int t = threadIdx.x;
  if (blk < 128) {
    int gid = blk * 256 + t;                  // 32768 threads
    int l  = gid & 63;
    int c  = gid >> 6;                        // 0..511
    int kt = c & 3;
    int f  = (c >> 2) & 15;
    int s  = c >> 6;
    int n  = f * 16 + (l & 15);
    int k0 = kt * 32 + (l >> 4) * 8;
    const float* src = B + (size_t)s * DIN * NOUT + n;
    uint32_t w0 = bf16_1(src[(size_t)(k0 + 0) * NOUT]) | (bf16_1(src[(size_t)(k0 + 1) * NOUT]) << 16);
    uint32_t w1 = bf16_1(src[(size_t)(k0 + 2) * NOUT]) | (bf16_1(src[(size_t)(k0 + 3) * NOUT]) << 16);
    uint32_t w2 = bf16_1(src[(size_t)(k0 + 4) * NOUT]) | (bf16_1(src[(size_t)(k0 + 5) * NOUT]) << 16);
    uint32_t w3 = bf16_1(src[(size_t)(k0 + 6) * NOUT]) | (bf16_1(src[(size_t)(k0 + 7) * NOUT]) << 16);
    u32x4 v = (u32x4){w0, w1, w2, w3};
    *(u32x4*)(ws + OFF_BF + (size_t)c * 1024 + (size_t)l * 16) = v;
  } else {
    __shared__ int bins[8];
    int* counts = (int*)(ws + OFF_META);
    if (t < 8) bins[t] = 0;
    __syncthreads();
    atomicAdd(&bins[sp[(blk - 128) * 256 + t] & 7], 1);
    __syncthreads();
    if (t < 8) atomicAdd(&counts[t], bins[t]);
  }
}

// Scatter: each block recomputes the 8-wide exclusive prefix of counts itself;
// block-local rank + one global cursor bump per species.
__global__ void k_scatter(const int* __restrict__ sp, char* __restrict__ ws) {
  __shared__ int lbin[8], gbase[8];
  int* counts = (int*)(ws + OFF_META);
  int* curs   = counts + 8;                   // zeroed by memsetAsync each call
  int* perm   = (int*)(ws + OFF_PERM);
  int t = threadIdx.x;
  if (t < 8) lbin[t] = 0;
  __syncthreads();
  int i = blockIdx.x * 256 + t;
  int s = sp[i] & 7;
  int rank = atomicAdd(&lbin[s], 1);          // within-block rank
  __syncthreads();
  if (t < 8) {
    int base = 0;
    #pragma unroll
    for (int j = 0; j < 8; ++j) base += (j < t) ? counts[j] : 0;
    gbase[t] = base + atomicAdd(&curs[t], lbin[t]);
  }
  __syncthreads();
  perm[gbase[s] + rank] = i;                  // order within species irrelevant
}

// One block = 64 rows (uniform species, via perm) x 256 cols. 4 waves, each 64x64.
// __launch_bounds__(256, 4): pin VGPR <= 128 so 4 blocks/CU (16 waves) stay
// resident — theory: R1/R2 gemm sat at 2 blocks/CU (VGPR just over 128) and
// couldn't hide the 900-cyc gather latency across its barrier-split phases.
__global__ __launch_bounds__(256, 4) void k_gemm(const float* __restrict__ A,
                                                 const char* __restrict__ ws,
                                                 float* __restrict__ out) {
  const int* counts = (const int*)(ws + OFF_META);
  const int* perm   = (const int*)(ws + OFF_PERM);
  const char* Bf    = ws + OFF_BF;

  __shared__ char As[BM * 256];   // [64 rows][128 k] bf16, XOR-swizzled
  __shared__ int prow[BM];

  // recompute bases/tile offsets from counts (8 uniform loads, register scan)
  int b = blockIdx.x;
  int s = -1, i = 0, rowStart = 0, nrows = 0;
  {
    int base = 0, toff = 0;
    #pragma unroll
    for (int j = 0; j < 8; ++j) {
      int c = counts[j];
      int nt = (c + BM - 1) >> 6;
      if (s < 0 && b < toff + nt) {
        s = j; i = b - toff;
        rowStart = base + i * BM;
        nrows = c - i * BM; if (nrows > BM) nrows = BM;
      }
      base += c; toff += nt;
    }
    if (s < 0) return;                        // past last tile
  }

  int t = threadIdx.x;
  if (t < BM) prow[t] = (t < nrows) ? perm[rowStart + t] : -1;
  __syncthreads();

  // stage A: 8 rows per iteration, 32 threads per row (float4 each), fp32->bf16
  // nontemporal loads: A is read-once streaming; keep L2 for B-frags + writes.
  int f4 = t & 31, r0 = t >> 5;
  #pragma unroll
  for (int it = 0; it < 8; ++it) {
    int r = r0 + it * 8;
    int rid = prow[r];
    u32x4 u = (u32x4){0u, 0u, 0u, 0u};
    if (rid >= 0) u = __builtin_nontemporal_load((const u32x4*)(A + (size_t)rid * DIN + f4 * 4));
    uint32_t lo = bf16_bits(u.x) | (bf16_bits(u.y) << 16);
    uint32_t hi = bf16_bits(u.z) | (bf16_bits(u.w) << 16);
    int off = (r * 256 + f4 * 8) ^ ((r & 7) << 4);   // G4 swizzle
    *(uint2*)(As + off) = make_uint2(lo, hi);
  }
  __syncthreads();

  int w = t >> 6, l = t & 63;
  f32x4 acc[4][4];
  #pragma unroll
  for (int mi = 0; mi < 4; ++mi)
    #pragma unroll
    for (int ni = 0; ni < 4; ++ni)
      acc[mi][ni] = (f32x4){0.f, 0.f, 0.f, 0.f};

  #pragma unroll
  for (int kt = 0; kt < 4; ++kt) {
    s16x8 afr[4];
    #pragma unroll
    for (int mi = 0; mi < 4; ++mi) {
      int r = mi * 16 + (l & 15);
      int off = (r * 256 + kt * 64 + (l >> 4) * 16) ^ ((r & 7) << 4);
      afr[mi] = *(const s16x8*)(As + off);
    }
    #pragma unroll
    for (int ni = 0; ni < 4; ++ni) {
      int c = (s * 16 + (w * 4 + ni)) * 4 + kt;
      s16x8 bfr = *(const s16x8*)(Bf + (size_t)c * 1024 + (size_t)l * 16);
      #pragma unroll
      for (int mi = 0; mi < 4; ++mi)
        acc[mi][ni] = __builtin_amdgcn_mfma_f32_16x16x32_bf16(afr[mi], bfr, acc[mi][ni], 0, 0, 0);
    }
  }

  // epilogue (R2 style — no barriers, stores pipeline freely; L2 write-back
  // merges the 64B segments from the 4 waves into full-line HBM writebacks)
  // D: row = (l>>4)*4 + q (+ mi*16), col = l&15 (+ ni*16 + w*64)
  int colBase = w * 64 + (l & 15);
  #pragma unroll
  for (int mi = 0; mi < 4; ++mi) {
    #pragma unroll
    for (int q = 0; q < 4; ++q) {
      int r = mi * 16 + ((l >> 4) << 2) + q;
      int rid = prow[r];
      if (rid >= 0) {
        #pragma unroll
        for (int ni = 0; ni < 4; ++ni)
          out[(size_t)rid * NOUT + colBase + ni * 16] = acc[mi][ni][q];
      }
    }
  }
}

// ws-free correctness fallback (only if ws_size is unexpectedly small)
__global__ void k_naive(const float* __restrict__ A, const int* __restrict__ sp,
                        const float* __restrict__ B, float* __restrict__ out) {
  __shared__ float av[DIN];
  int m = blockIdx.x;
  int n = threadIdx.x;
  if (n < DIN) av[n] = A[(size_t)m * DIN + n];
  __syncthreads();
  int s = sp[m] & 7;
  const float* b = B + (size_t)s * DIN * NOUT + n;
  float acc = 0.f;
  #pragma unroll 8
  for (int k = 0; k < DIN; ++k) acc = fmaf(av[k], b[(size_t)k * NOUT], acc);
  out[(size_t)m * NOUT + n] = acc;
}

extern "C" void kernel_launch(void* const* d_in, const int* in_sizes, int n_in,
                              void* d_out, int out_size, void* d_ws, size_t ws_size,
                              hipStream_t stream) {
  const float* values = (const float*)d_in[0];
  const int*   sp     = (const int*)d_in[1];
  const float* B      = (const float*)d_in[2];
  float*       out    = (float*)d_out;

  if (d_ws == nullptr || ws_size < WS_NEEDED) {
    k_naive<<<MROWS, NOUT, 0, stream>>>(values, sp, B, out);
    return;
  }
  char* ws = (char*)d_ws;
  (void)hipMemsetAsync(ws + OFF_META, 0, 64, stream);           // counts+curs = 0
  k_convert_hist<<<128 + MROWS / 256, 256, 0, stream>>>(B, sp, ws);
  k_scatter<<<MROWS / 256, 256, 0, stream>>>(sp, ws);
  k_gemm<<<MROWS / BM + NSPEC, 256, 0, stream>>>(values, ws, out);
}

// Round 6
// 61.399 us; speedup vs baseline: 1.1959x; 1.1837x over previous
//
#include <hip/hip_runtime.h>
#include <stdint.h>

#define MROWS 131072
#define NSPEC 8
#define DIN   128
#define NOUT  256
#define BM    64

typedef __attribute__((ext_vector_type(8))) short s16x8;
typedef __attribute__((ext_vector_type(4))) float f32x4;

// workspace layout
#define OFF_BF    ((size_t)0)        // 8*16*4*1024 = 524288 B : W in bf16, fragment order
#define OFF_PERM  ((size_t)524288)   // M*4 = 524288 B : row permutation (sorted by species)
#define OFF_META  ((size_t)1048576)  // ints: counts[8], cursors[8]  (zeroed by memsetAsync)
#define WS_NEEDED ((size_t)(1048576 + 256))

__device__ __forceinline__ uint32_t bf16_bits(uint32_t u) {
  return (u + 0x7FFFu + ((u >> 16) & 1u)) >> 16;   // RNE, inputs finite
}
__device__ __forceinline__ uint32_t bf16_1(float f) {
  union { float f; uint32_t u; } v; v.f = f;
  return bf16_bits(v.u);
}

// blocks 0..127: convert W [8][128][256] fp32 -> bf16 fragment order.
//   chunk c = ((s*16 + nfrag)*4 + kt); lane l holds
//   B[k = kt*32 + (l>>4)*8 + j][n = nfrag*16 + (l&15)], j=0..7 (16B contiguous).
// blocks 128..639: histogram species -> counts[8] (curs zeroed by memset).
__global__ void k_convert_hist(const float* __restrict__ B, const int* __restrict__ sp,
                               char* __restrict__ ws) {
  int blk = blockIdx.x;
  int t = threadIdx.x;
  if (blk < 128) {
    int gid = blk * 256 + t;                  // 32768 threads
    int l  = gid & 63;
    int c  = gid >> 6;                        // 0..511
    int kt = c & 3;
    int f  = (c >> 2) & 15;
    int s  = c >> 6;
    int n  = f * 16 + (l & 15);
    int k0 = kt * 32 + (l >> 4) * 8;
    const float* src = B + (size_t)s * DIN * NOUT + n;
    uint32_t w0 = bf16_1(src[(size_t)(k0 + 0) * NOUT]) | (bf16_1(src[(size_t)(k0 + 1) * NOUT]) << 16);
    uint32_t w1 = bf16_1(src[(size_t)(k0 + 2) * NOUT]) | (bf16_1(src[(size_t)(k0 + 3) * NOUT]) << 16);
    uint32_t w2 = bf16_1(src[(size_t)(k0 + 4) * NOUT]) | (bf16_1(src[(size_t)(k0 + 5) * NOUT]) << 16);
    uint32_t w3 = bf16_1(src[(size_t)(k0 + 6) * NOUT]) | (bf16_1(src[(size_t)(k0 + 7) * NOUT]) << 16);
    *(uint4*)(ws + OFF_BF + (size_t)c * 1024 + (size_t)l * 16) = make_uint4(w0, w1, w2, w3);
  } else {
    __shared__ int bins[8];
    int* counts = (int*)(ws + OFF_META);
    if (t < 8) bins[t] = 0;
    __syncthreads();
    atomicAdd(&bins[sp[(blk - 128) * 256 + t] & 7], 1);
    __syncthreads();
    if (t < 8) atomicAdd(&counts[t], bins[t]);
  }
}

// Scatter: each block recomputes the 8-wide exclusive prefix of counts itself;
// block-local rank + one global cursor bump per species.
__global__ void k_scatter(const int* __restrict__ sp, char* __restrict__ ws) {
  __shared__ int lbin[8], gbase[8];
  int* counts = (int*)(ws + OFF_META);
  int* curs   = counts + 8;                   // zeroed by memsetAsync each call
  int* perm   = (int*)(ws + OFF_PERM);
  int t = threadIdx.x;
  if (t < 8) lbin[t] = 0;
  __syncthreads();
  int i = blockIdx.x * 256 + t;
  int s = sp[i] & 7;
  int rank = atomicAdd(&lbin[s], 1);          // within-block rank
  __syncthreads();
  if (t < 8) {
    int base = 0;
    #pragma unroll
    for (int j = 0; j < 8; ++j) base += (j < t) ? counts[j] : 0;
    gbase[t] = base + atomicAdd(&curs[t], lbin[t]);
  }
  __syncthreads();
  perm[gbase[s] + rank] = i;                  // order within species irrelevant
}

// One block = 64 rows (uniform species, via perm) x 256 cols. 4 waves, each 64x64.
// lb(256,4): request 4 blocks/CU (VGPR<=128). Structure needs ~116 VGPR -> no spill expected.
__global__ __launch_bounds__(256, 4) void k_gemm(const float* __restrict__ A,
                                                 const char* __restrict__ ws,
                                                 float* __restrict__ out) {
  const int* counts = (const int*)(ws + OFF_META);
  const int* perm   = (const int*)(ws + OFF_PERM);
  const char* Bf    = ws + OFF_BF;

  __shared__ char As[BM * 256];   // [64 rows][128 k] bf16, XOR-swizzled
  __shared__ int prow[BM];

  // recompute bases/tile offsets from counts (8 uniform loads, register scan)
  int b = blockIdx.x;
  int s = -1, i = 0, rowStart = 0, nrows = 0;
  {
    int base = 0, toff = 0;
    #pragma unroll
    for (int j = 0; j < 8; ++j) {
      int c = counts[j];
      int nt = (c + BM - 1) >> 6;
      if (s < 0 && b < toff + nt) {
        s = j; i = b - toff;
        rowStart = base + i * BM;
        nrows = c - i * BM; if (nrows > BM) nrows = BM;
      }
      base += c; toff += nt;
    }
    if (s < 0) return;                        // past last tile
  }

  int t = threadIdx.x;
  if (t < BM) prow[t] = (t < nrows) ? perm[rowStart + t] : -1;
  __syncthreads();

  // stage A: 8 rows per iteration, 32 threads per row (float4 each), fp32->bf16
  int f4 = t & 31, r0 = t >> 5;
  #pragma unroll
  for (int it = 0; it < 8; ++it) {
    int r = r0 + it * 8;
    int rid = prow[r];
    float4 v = make_float4(0.f, 0.f, 0.f, 0.f);
    if (rid >= 0) v = *(const float4*)(A + (size_t)rid * DIN + f4 * 4);
    uint32_t lo = bf16_1(v.x) | (bf16_1(v.y) << 16);
    uint32_t hi = bf16_1(v.z) | (bf16_1(v.w) << 16);
    int off = (r * 256 + f4 * 8) ^ ((r & 7) << 4);   // G4 swizzle
    *(uint2*)(As + off) = make_uint2(lo, hi);
  }
  __syncthreads();

  int w = t >> 6, l = t & 63;
  f32x4 acc[4][4];
  #pragma unroll
  for (int mi = 0; mi < 4; ++mi)
    #pragma unroll
    for (int ni = 0; ni < 4; ++ni)
      acc[mi][ni] = (f32x4){0.f, 0.f, 0.f, 0.f};

  #pragma unroll
  for (int kt = 0; kt < 4; ++kt) {
    s16x8 afr[4];
    #pragma unroll
    for (int mi = 0; mi < 4; ++mi) {
      int r = mi * 16 + (l & 15);
      int off = (r * 256 + kt * 64 + (l >> 4) * 16) ^ ((r & 7) << 4);
      afr[mi] = *(const s16x8*)(As + off);
    }
    #pragma unroll
    for (int ni = 0; ni < 4; ++ni) {
      int c = (s * 16 + (w * 4 + ni)) * 4 + kt;
      s16x8 bfr = *(const s16x8*)(Bf + (size_t)c * 1024 + (size_t)l * 16);
      #pragma unroll
      for (int mi = 0; mi < 4; ++mi)
        acc[mi][ni] = __builtin_amdgcn_mfma_f32_16x16x32_bf16(afr[mi], bfr, acc[mi][ni], 0, 0, 0);
    }
  }

  // D: row = (l>>4)*4 + q (+ mi*16), col = l&15 (+ ni*16 + w*64)
  int colBase = w * 64 + (l & 15);
  #pragma unroll
  for (int mi = 0; mi < 4; ++mi) {
    #pragma unroll
    for (int q = 0; q < 4; ++q) {
      int r = mi * 16 + ((l >> 4) << 2) + q;
      int rid = prow[r];
      if (rid >= 0) {
        #pragma unroll
        for (int ni = 0; ni < 4; ++ni)
          out[(size_t)rid * NOUT + colBase + ni * 16] = acc[mi][ni][q];
      }
    }
  }
}

// ws-free correctness fallback (only if ws_size is unexpectedly small)
__global__ void k_naive(const float* __restrict__ A, const int* __restrict__ sp,
                        const float* __restrict__ B, float* __restrict__ out) {
  __shared__ float av[DIN];
  int m = blockIdx.x;
  int n = threadIdx.x;
  if (n < DIN) av[n] = A[(size_t)m * DIN + n];
  __syncthreads();
  int s = sp[m] & 7;
  const float* b = B + (size_t)s * DIN * NOUT + n;
  float acc = 0.f;
  #pragma unroll 8
  for (int k = 0; k < DIN; ++k) acc = fmaf(av[k], b[(size_t)k * NOUT], acc);
  out[(size_t)m * NOUT + n] = acc;
}

extern "C" void kernel_launch(void* const* d_in, const int* in_sizes, int n_in,
                              void* d_out, int out_size, void* d_ws, size_t ws_size,
                              hipStream_t stream) {
  const float* values = (const float*)d_in[0];
  const int*   sp     = (const int*)d_in[1];
  const float* B      = (const float*)d_in[2];
  float*       out    = (float*)d_out;

  if (d_ws == nullptr || ws_size < WS_NEEDED) {
    k_naive<<<MROWS, NOUT, 0, stream>>>(values, sp, B, out);
    return;
  }
  char* ws = (char*)d_ws;
  (void)hipMemsetAsync(ws + OFF_META, 0, 64, stream);           // counts+curs = 0
  k_convert_hist<<<128 + MROWS / 256, 256, 0, stream>>>(B, sp, ws);
  k_scatter<<<MROWS / 256, 256, 0, stream>>>(sp, ws);
  k_gemm<<<MROWS / BM + NSPEC, 256, 0, stream>>>(values, ws, out);
}

// Round 7
// 61.041 us; speedup vs baseline: 1.2030x; 1.0059x over previous
//
#include <hip/hip_runtime.h>
#include <stdint.h>

#define MROWS 131072
#define NSPEC 8
#define DIN   128
#define NOUT  256
#define BM    32

typedef __attribute__((ext_vector_type(8))) short s16x8;
typedef __attribute__((ext_vector_type(4))) float f32x4;

// workspace layout
#define OFF_BF    ((size_t)0)        // 8*16*4*1024 = 524288 B : W in bf16, fragment order
#define OFF_PERM  ((size_t)524288)   // M*4 = 524288 B : row permutation (sorted by species)
#define OFF_META  ((size_t)1048576)  // ints: counts[8], cursors[8]  (zeroed by memsetAsync)
#define WS_NEEDED ((size_t)(1048576 + 256))

__device__ __forceinline__ uint32_t bf16_bits(uint32_t u) {
  return (u + 0x7FFFu + ((u >> 16) & 1u)) >> 16;   // RNE, inputs finite
}
__device__ __forceinline__ uint32_t bf16_1(float f) {
  union { float f; uint32_t u; } v; v.f = f;
  return bf16_bits(v.u);
}

// blocks 0..127: convert W [8][128][256] fp32 -> bf16 fragment order.
//   chunk c = ((s*16 + nfrag)*4 + kt); lane l holds
//   B[k = kt*32 + (l>>4)*8 + j][n = nfrag*16 + (l&15)], j=0..7 (16B contiguous).
// blocks 128..639: histogram species -> counts[8] (curs zeroed by memset).
__global__ void k_convert_hist(const float* __restrict__ B, const int* __restrict__ sp,
                               char* __restrict__ ws) {
  int blk = blockIdx.x;
  int t = threadIdx.x;
  if (blk < 128) {
    int gid = blk * 256 + t;                  // 32768 threads
    int l  = gid & 63;
    int c  = gid >> 6;                        // 0..511
    int kt = c & 3;
    int f  = (c >> 2) & 15;
    int s  = c >> 6;
    int n  = f * 16 + (l & 15);
    int k0 = kt * 32 + (l >> 4) * 8;
    const float* src = B + (size_t)s * DIN * NOUT + n;
    uint32_t w0 = bf16_1(src[(size_t)(k0 + 0) * NOUT]) | (bf16_1(src[(size_t)(k0 + 1) * NOUT]) << 16);
    uint32_t w1 = bf16_1(src[(size_t)(k0 + 2) * NOUT]) | (bf16_1(src[(size_t)(k0 + 3) * NOUT]) << 16);
    uint32_t w2 = bf16_1(src[(size_t)(k0 + 4) * NOUT]) | (bf16_1(src[(size_t)(k0 + 5) * NOUT]) << 16);
    uint32_t w3 = bf16_1(src[(size_t)(k0 + 6) * NOUT]) | (bf16_1(src[(size_t)(k0 + 7) * NOUT]) << 16);
    *(uint4*)(ws + OFF_BF + (size_t)c * 1024 + (size_t)l * 16) = make_uint4(w0, w1, w2, w3);
  } else {
    __shared__ int bins[8];
    int* counts = (int*)(ws + OFF_META);
    if (t < 8) bins[t] = 0;
    __syncthreads();
    atomicAdd(&bins[sp[(blk - 128) * 256 + t] & 7], 1);
    __syncthreads();
    if (t < 8) atomicAdd(&counts[t], bins[t]);
  }
}

// Scatter: each block recomputes the 8-wide exclusive prefix of counts itself;
// block-local rank + one global cursor bump per species.
__global__ void k_scatter(const int* __restrict__ sp, char* __restrict__ ws) {
  __shared__ int lbin[8], gbase[8];
  int* counts = (int*)(ws + OFF_META);
  int* curs   = counts + 8;                   // zeroed by memsetAsync each call
  int* perm   = (int*)(ws + OFF_PERM);
  int t = threadIdx.x;
  if (t < 8) lbin[t] = 0;
  __syncthreads();
  int i = blockIdx.x * 256 + t;
  int s = sp[i] & 7;
  int rank = atomicAdd(&lbin[s], 1);          // within-block rank
  __syncthreads();
  if (t < 8) {
    int base = 0;
    #pragma unroll
    for (int j = 0; j < 8; ++j) base += (j < t) ? counts[j] : 0;
    gbase[t] = base + atomicAdd(&curs[t], lbin[t]);
  }
  __syncthreads();
  perm[gbase[s] + rank] = i;                  // order within species irrelevant
}

// One block = 32 rows (uniform species, via perm) x 256 cols. 4 waves, each 32x64.
// BM=32 + lb(256,5): smaller gather/store bursts + 5 blocks/CU (20 waves) for
// finer cross-block phase overlap -> higher memory duty cycle (theory R7).
__global__ __launch_bounds__(256, 5) void k_gemm(const float* __restrict__ A,
                                                 const char* __restrict__ ws,
                                                 float* __restrict__ out) {
  const int* counts = (const int*)(ws + OFF_META);
  const int* perm   = (const int*)(ws + OFF_PERM);
  const char* Bf    = ws + OFF_BF;

  __shared__ char As[BM * 256];   // [32 rows][128 k] bf16, XOR-swizzled (8 KB)
  __shared__ int prow[BM];

  // recompute bases/tile offsets from counts (8 uniform loads, register scan)
  int b = blockIdx.x;
  int s = -1, i = 0, rowStart = 0, nrows = 0;
  {
    int base = 0, toff = 0;
    #pragma unroll
    for (int j = 0; j < 8; ++j) {
      int c = counts[j];
      int nt = (c + BM - 1) >> 5;
      if (s < 0 && b < toff + nt) {
        s = j; i = b - toff;
        rowStart = base + i * BM;
        nrows = c - i * BM; if (nrows > BM) nrows = BM;
      }
      base += c; toff += nt;
    }
    if (s < 0) return;                        // past last tile
  }

  int t = threadIdx.x;
  // perm entries for this thread's 4 stage rows -> registers (no barrier needed)
  int rud[4];
  #pragma unroll
  for (int it = 0; it < 4; ++it) {
    int r = (t >> 5) + it * 8;
    rud[it] = (r < nrows) ? perm[rowStart + r] : -1;
  }
  if (t < BM) prow[t] = (t < nrows) ? perm[rowStart + t] : -1;   // epilogue lookup

  // stage A: 8 rows per iteration, 32 threads per row (float4 each), fp32->bf16
  int f4 = t & 31;
  #pragma unroll
  for (int it = 0; it < 4; ++it) {
    int r = (t >> 5) + it * 8;
    int rid = rud[it];
    float4 v = make_float4(0.f, 0.f, 0.f, 0.f);
    if (rid >= 0) v = *(const float4*)(A + (size_t)rid * DIN + f4 * 4);
    uint32_t lo = bf16_1(v.x) | (bf16_1(v.y) << 16);
    uint32_t hi = bf16_1(v.z) | (bf16_1(v.w) << 16);
    int off = (r * 256 + f4 * 8) ^ ((r & 7) << 4);   // G4 swizzle
    *(uint2*)(As + off) = make_uint2(lo, hi);
  }
  __syncthreads();

  int w = t >> 6, l = t & 63;
  f32x4 acc[2][4];
  #pragma unroll
  for (int mi = 0; mi < 2; ++mi)
    #pragma unroll
    for (int ni = 0; ni < 4; ++ni)
      acc[mi][ni] = (f32x4){0.f, 0.f, 0.f, 0.f};

  #pragma unroll
  for (int kt = 0; kt < 4; ++kt) {
    s16x8 afr[2];
    #pragma unroll
    for (int mi = 0; mi < 2; ++mi) {
      int r = mi * 16 + (l & 15);
      int off = (r * 256 + kt * 64 + (l >> 4) * 16) ^ ((r & 7) << 4);
      afr[mi] = *(const s16x8*)(As + off);
    }
    #pragma unroll
    for (int ni = 0; ni < 4; ++ni) {
      int c = (s * 16 + (w * 4 + ni)) * 4 + kt;
      s16x8 bfr = *(const s16x8*)(Bf + (size_t)c * 1024 + (size_t)l * 16);
      #pragma unroll
      for (int mi = 0; mi < 2; ++mi)
        acc[mi][ni] = __builtin_amdgcn_mfma_f32_16x16x32_bf16(afr[mi], bfr, acc[mi][ni], 0, 0, 0);
    }
  }

  // D: row = (l>>4)*4 + q (+ mi*16), col = l&15 (+ ni*16 + w*64)
  int colBase = w * 64 + (l & 15);
  #pragma unroll
  for (int mi = 0; mi < 2; ++mi) {
    #pragma unroll
    for (int q = 0; q < 4; ++q) {
      int r = mi * 16 + ((l >> 4) << 2) + q;
      int rid = prow[r];
      if (rid >= 0) {
        #pragma unroll
        for (int ni = 0; ni < 4; ++ni)
          out[(size_t)rid * NOUT + colBase + ni * 16] = acc[mi][ni][q];
      }
    }
  }
}

// ws-free correctness fallback (only if ws_size is unexpectedly small)
__global__ void k_naive(const float* __restrict__ A, const int* __restrict__ sp,
                        const float* __restrict__ B, float* __restrict__ out) {
  __shared__ float av[DIN];
  int m = blockIdx.x;
  int n = threadIdx.x;
  if (n < DIN) av[n] = A[(size_t)m * DIN + n];
  __syncthreads();
  int s = sp[m] & 7;
  const float* b = B + (size_t)s * DIN * NOUT + n;
  float acc = 0.f;
  #pragma unroll 8
  for (int k = 0; k < DIN; ++k) acc = fmaf(av[k], b[(size_t)k * NOUT], acc);
  out[(size_t)m * NOUT + n] = acc;
}

extern "C" void kernel_launch(void* const* d_in, const int* in_sizes, int n_in,
                              void* d_out, int out_size, void* d_ws, size_t ws_size,
                              hipStream_t stream) {
  const float* values = (const float*)d_in[0];
  const int*   sp     = (const int*)d_in[1];
  const float* B      = (const float*)d_in[2];
  float*       out    = (float*)d_out;

  if (d_ws == nullptr || ws_size < WS_NEEDED) {
    k_naive<<<MROWS, NOUT, 0, stream>>>(values, sp, B, out);
    return;
  }
  char* ws = (char*)d_ws;
  (void)hipMemsetAsync(ws + OFF_META, 0, 64, stream);           // counts+curs = 0
  k_convert_hist<<<128 + MROWS / 256, 256, 0, stream>>>(B, sp, ws);
  k_scatter<<<MROWS / 256, 256, 0, stream>>>(sp, ws);
  k_gemm<<<MROWS / BM + NSPEC, 256, 0, stream>>>(values, ws, out);
}